// Round 11
// baseline (217.101 us; speedup 1.0000x reference)
//
#include <hip/hip_runtime.h>
#include <math.h>

// Problem constants: L=16384, H=256, P=512.
#define L_SEQ 16384
#define H_DIM 256
#define P_DIM 512
#define CL 32                 // scan chunk length == GEMM2 row-tile
#define NC (L_SEQ / CL)       // 512 chunks

typedef __attribute__((ext_vector_type(8))) short bf16x8;   // MFMA A/B fragment (4 VGPR)
typedef __attribute__((ext_vector_type(4))) float f32x4;    // MFMA C/D fragment

static __device__ __forceinline__ unsigned short f2bf(float f) {
  unsigned int u = __builtin_bit_cast(unsigned int, f);
  u += 0x7FFFu + ((u >> 16) & 1u);
  return (unsigned short)(u >> 16);
}
static __device__ __forceinline__ float bflo(unsigned int v) {
  return __builtin_bit_cast(float, v << 16);
}
static __device__ __forceinline__ float bfhi(unsigned int v) {
  return __builtin_bit_cast(float, v & 0xFFFF0000u);
}
static __device__ __forceinline__ float bf2f(unsigned short s) {
  return __builtin_bit_cast(float, (unsigned int)s << 16);
}

// Merged prep (branch by blockIdx, wave-uniform):
//  [0,2): params; [2,1026): W1b; [1026,2050): W2b; [2050,6146): cast u->ub
__global__ __launch_bounds__(256) void prep_all(
    const float* __restrict__ A_diag, const float* __restrict__ G_diag,
    const float* __restrict__ dt, const float* __restrict__ B,
    const float* __restrict__ C, const float* __restrict__ u,
    float* __restrict__ prm, unsigned short* __restrict__ W1b,
    unsigned short* __restrict__ W2b, unsigned short* __restrict__ ub) {
  const int b = blockIdx.x;
  const int t = threadIdx.x;
  if (b < 2) {
    int p = b * 256 + t;
    float dts = 1.0f / (1.0f + expf(-dt[p]));
    float G = fmaxf(G_diag[p], 0.0f);
    float g = dts * G;
    float root = sqrtf(1.0f - g);
    float denom = fmaxf(dts * dts, 1e-6f);
    float A_low  = (2.0f - g - 2.0f * root) / denom;
    float A_high = (2.0f - g + 2.0f * root) / denom;
    float Ad = A_diag[p];
    float A = A_low + fmaxf(Ad - A_low, 0.0f) - fmaxf(Ad - A_high, 0.0f);
    float m00 = 1.0f - g;
    float m01 = -dts * A;
    float m10 = dts * (1.0f - g);
    float m11 = 1.0f - dts * dts * A;
    float c00 = m00, c01 = m01, c10 = m10, c11 = m11;
#pragma unroll
    for (int i = 0; i < 5; i++) {   // M^32 by squaring (CL=32); rho(M)<=1
      float n00 = c00 * c00 + c01 * c10;
      float n01 = c00 * c01 + c01 * c11;
      float n10 = c10 * c00 + c11 * c10;
      float n11 = c10 * c01 + c11 * c11;
      c00 = n00; c01 = n01; c10 = n10; c11 = n11;
    }
    prm[0 * P_DIM + p] = m00;
    prm[1 * P_DIM + p] = m01;
    prm[2 * P_DIM + p] = m10;
    prm[3 * P_DIM + p] = m11;
    prm[4 * P_DIM + p] = dts;
    prm[5 * P_DIM + p] = dts * dts;
    prm[6 * P_DIM + p] = c00;
    prm[7 * P_DIM + p] = c01;
    prm[8 * P_DIM + p] = c10;
    prm[9 * P_DIM + p] = c11;
  } else if (b < 2 + 1024) {
    int idx = (b - 2) * 256 + t;          // W1b[n][k], n=2p+c, k=h
    int n = idx >> 8;
    int k = idx & 255;
    int p = n >> 1, c = n & 1;
    W1b[idx] = f2bf(B[(p * H_DIM + k) * 2 + c]);
  } else if (b < 2 + 2048) {
    int idx = (b - 1026) * 256 + t;       // W2b[n][k], n=h, k=2p+c
    int h = idx >> 10;
    int k = idx & 1023;
    int p = k >> 1, c = k & 1;
    float v = C[(h * P_DIM + p) * 2 + c];
    W2b[idx] = f2bf(c ? -v : v);
  } else {
    int idx = (b - 2050) * 256 + t;       // cast u
    float4 v = ((const float4*)u)[idx];
    ushort4 o;
    o.x = f2bf(v.x); o.y = f2bf(v.y); o.z = f2bf(v.z); o.w = f2bf(v.w);
    ((ushort4*)ub)[idx] = o;
  }
}

// GEMM1 + fused local scan. 128x128 tile, 256 threads = 4 waves (2x2), BK=32.
// A[M][K]=ub bf16 row-major, W[N][K]=W1b bf16 (pre-transposed), fp32 acc, bf16 out.
// Epilogue: write Bu16 tile, fence, then each thread scans one (chunk, p) column
// of the just-written tile (L1/L2-hot re-read, numerics identical to standalone
// scan_local) and emits the chunk-final state.
__global__ __launch_bounds__(256) void gemm1_scan(
    const unsigned short* __restrict__ A, const unsigned short* __restrict__ W,
    unsigned short* __restrict__ Out,           // Bu16, N=1024
    const float* __restrict__ prm, float4* __restrict__ finals) {
  constexpr int BM = 128, BN = 128, N = 1024, K = H_DIM;
  __shared__ unsigned short tA[BM * 32];   // linear (gload_lds dest)
  __shared__ unsigned short tW[BN * 32];
  const int tid = threadIdx.x;
  const int lane = tid & 63;
  const int wid = tid >> 6;
  const int wr = wid >> 1;
  const int wc = wid & 1;
  const int bm = blockIdx.x * BM;
  const int bn = blockIdx.y * BN;

  f32x4 acc[4][4] = {};

  const int srow = lane >> 2;
  const int soff = (lane & 3) * 8;

  for (int k0 = 0; k0 < K; k0 += 32) {
    __syncthreads();
#pragma unroll
    for (int c = wid; c < BM / 16; c += 4) {
      const unsigned short* src = A + (size_t)(bm + c * 16 + srow) * K + k0 + soff;
      __builtin_amdgcn_global_load_lds(
          (const __attribute__((address_space(1))) void*)src,
          (__attribute__((address_space(3))) void*)(tA + c * 512), 16, 0, 0);
    }
#pragma unroll
    for (int c = wid; c < BN / 16; c += 4) {
      const unsigned short* src = W + (size_t)(bn + c * 16 + srow) * K + k0 + soff;
      __builtin_amdgcn_global_load_lds(
          (const __attribute__((address_space(1))) void*)src,
          (__attribute__((address_space(3))) void*)(tW + c * 512), 16, 0, 0);
    }
    __syncthreads();

    const int rA = lane & 15;
    const int kc = (lane >> 4) * 8;
    bf16x8 af[4], wf[4];
#pragma unroll
    for (int i = 0; i < 4; i++)
      af[i] = *(const bf16x8*)&tA[(wr * 64 + i * 16 + rA) * 32 + kc];
#pragma unroll
    for (int j = 0; j < 4; j++)
      wf[j] = *(const bf16x8*)&tW[(wc * 64 + j * 16 + rA) * 32 + kc];
#pragma unroll
    for (int i = 0; i < 4; i++)
#pragma unroll
      for (int j = 0; j < 4; j++)
        acc[i][j] = __builtin_amdgcn_mfma_f32_16x16x32_bf16(af[i], wf[j], acc[i][j], 0, 0, 0);
  }

  // C/D layout: col = lane&15, row = (lane>>4)*4 + q  [m89-verified]
  const int cr = (lane >> 4) * 4;
  const int cc = lane & 15;
#pragma unroll
  for (int i = 0; i < 4; i++)
#pragma unroll
    for (int j = 0; j < 4; j++) {
      const int row0 = bm + wr * 64 + i * 16 + cr;
      const int col = bn + wc * 64 + j * 16 + cc;
#pragma unroll
      for (int q = 0; q < 4; q++)
        Out[(size_t)(row0 + q) * N + col] = f2bf(acc[i][j][q]);
    }

  // ---- fused local scan over this block's 4 chunks x 64 p-states
  __threadfence();     // make this block's global writes visible to its own reads
  __syncthreads();
  {
    const int i = tid >> 6;            // chunk within tile (0..3) — one per wave
    const int pl = tid & 63;           // p within tile
    const int p = (bn >> 1) + pl;      // global p
    const int cglob = blockIdx.x * 4 + i;
    float m00 = prm[0 * P_DIM + p], m01 = prm[1 * P_DIM + p];
    float m10 = prm[2 * P_DIM + p], m11 = prm[3 * P_DIM + p];
    float dts = prm[4 * P_DIM + p], dts2 = prm[5 * P_DIM + p];
    float x1r = 0.f, x2r = 0.f, x1i = 0.f, x2i = 0.f;
    const unsigned int* src =
        (const unsigned int*)Out + (size_t)(bm + i * 32) * (N / 2) + p;
#pragma unroll 8
    for (int s = 0; s < CL; s++) {
      unsigned int v = src[(size_t)s * (N / 2)];
      float bx = bflo(v), by = bfhi(v);
      float n1r = fmaf(m00, x1r, fmaf(m01, x2r, dts * bx));
      float n2r = fmaf(m10, x1r, fmaf(m11, x2r, dts2 * bx));
      float n1i = fmaf(m00, x1i, fmaf(m01, x2i, dts * by));
      float n2i = fmaf(m10, x1i, fmaf(m11, x2i, dts2 * by));
      x1r = n1r; x2r = n2r; x1i = n1i; x2i = n2i;
    }
    finals[(size_t)cglob * P_DIM + p] = make_float4(x1r, x2r, x1i, x2i);
  }
}

// Phase B: Hillis-Steele over NC=512 chunks, one block per p, 512 threads.
__global__ __launch_bounds__(NC) void scan_carry(
    const float4* __restrict__ finals, const float* __restrict__ prm,
    float4* __restrict__ carry) {
  int p = blockIdx.x;
  int c = threadIdx.x;
  __shared__ float4 sb[NC];
  float m00 = prm[6 * P_DIM + p], m01 = prm[7 * P_DIM + p];
  float m10 = prm[8 * P_DIM + p], m11 = prm[9 * P_DIM + p];
  float4 b = finals[c * P_DIM + p];
  for (int o = 1; o < NC; o <<= 1) {
    sb[c] = b;
    __syncthreads();
    float4 nb = (c >= o) ? sb[c - o] : make_float4(0.f, 0.f, 0.f, 0.f);
    __syncthreads();
    b.x = fmaf(m00, nb.x, fmaf(m01, nb.y, b.x));
    b.y = fmaf(m10, nb.x, fmaf(m11, nb.y, b.y));
    b.z = fmaf(m00, nb.z, fmaf(m01, nb.w, b.z));
    b.w = fmaf(m10, nb.z, fmaf(m11, nb.w, b.w));
    float n00 = m00 * m00 + m01 * m10;
    float n01 = m00 * m01 + m01 * m11;
    float n10 = m10 * m00 + m11 * m10;
    float n11 = m10 * m01 + m11 * m11;
    m00 = n00; m01 = n01; m10 = n10; m11 = n11;
  }
  if (c + 1 < NC) carry[(c + 1) * P_DIM + p] = b;
  if (c == 0) carry[p] = make_float4(0.f, 0.f, 0.f, 0.f);
}

// GEMM2 with fused scan_final: block = 32 rows (one CL chunk) x full N=256.
// Prologue: recompute ys for the 32 rows from Bu16 + carry (fp32 recurrence),
// deposit bf16 into XOR-swizzled LDS A-tile (T2: byte ^= (row&7)<<4).
// K-loop: A from LDS (no staging), W2b tile via global_load_lds (16KB/step).
// Epilogue: out = acc + ub*D (fp32 out).
__global__ __launch_bounds__(256) void gemm2_fused(
    const unsigned int* __restrict__ Bu16, const float* __restrict__ prm,
    const float4* __restrict__ carry, const unsigned short* __restrict__ W2b,
    const unsigned short* __restrict__ ub, const float* __restrict__ Dv,
    float* __restrict__ out) {
  __shared__ unsigned int yA[32 * 512];       // 64KB: ys[row][p] packed bf16 (re,im), swizzled
  __shared__ unsigned short tW[256 * 32];     // 16KB W2b K-tile (linear, gload_lds dest)
  const int tid = threadIdx.x;
  const int lane = tid & 63;
  const int wid = tid >> 6;
  const int row0 = blockIdx.x * 32;

  // ---- prologue: 2 p-columns per thread, 32-step recurrence
#pragma unroll
  for (int h = 0; h < 2; h++) {
    const int p = tid + h * 256;
    float m00 = prm[0 * P_DIM + p], m01 = prm[1 * P_DIM + p];
    float m10 = prm[2 * P_DIM + p], m11 = prm[3 * P_DIM + p];
    float dts = prm[4 * P_DIM + p], dts2 = prm[5 * P_DIM + p];
    float4 s = carry[(size_t)blockIdx.x * P_DIM + p];
    float x1r = s.x, x2r = s.y, x1i = s.z, x2i = s.w;
    const unsigned int* src = Bu16 + (size_t)row0 * P_DIM + p;
#pragma unroll 8
    for (int i = 0; i < 32; i++) {
      unsigned int v = src[(size_t)i * P_DIM];
      float bx = bflo(v), by = bfhi(v);
      float n1r = fmaf(m00, x1r, fmaf(m01, x2r, dts * bx));
      float n2r = fmaf(m10, x1r, fmaf(m11, x2r, dts2 * bx));
      float n1i = fmaf(m00, x1i, fmaf(m01, x2i, dts * by));
      float n2i = fmaf(m10, x1i, fmaf(m11, x2i, dts2 * by));
      // swizzled store: uint index (i*512+p) ^ ((i&7)<<2)  == byte ^ ((i&7)<<4)
      yA[(i * 512 + p) ^ ((i & 7) << 2)] =
          (unsigned int)f2bf(n2r) | ((unsigned int)f2bf(n2i) << 16);
      x1r = n1r; x2r = n2r; x1i = n1i; x2i = n2i;
    }
  }

  // ---- K-loop: 32 steps of BK=32 over K=1024
  const int srow = lane >> 2;
  const int soff = (lane & 3) * 8;
  const int wr = wid >> 1;          // row half (16 rows)
  const int wc = wid & 1;           // col half (128 cols)
  const int rA = lane & 15;
  const int kc = (lane >> 4) * 8;
  const int arow = wr * 16 + rA;
  const unsigned short* yAs = (const unsigned short*)yA;
  f32x4 acc[8] = {};

  for (int k0 = 0; k0 < 1024; k0 += 32) {
    __syncthreads();   // first iteration also fences prologue LDS writes
#pragma unroll
    for (int c = wid; c < 16; c += 4) {
      const unsigned short* src = W2b + (size_t)(c * 16 + srow) * 1024 + k0 + soff;
      __builtin_amdgcn_global_load_lds(
          (const __attribute__((address_space(1))) void*)src,
          (__attribute__((address_space(3))) void*)(tW + c * 512), 16, 0, 0);
    }
    __syncthreads();

    // A-frag from swizzled LDS: short index (arow*1024 + k) ^ ((arow&7)<<3)
    bf16x8 af = *(const bf16x8*)&yAs[((size_t)arow * 1024 + k0 + kc) ^ ((arow & 7) << 3)];
#pragma unroll
    for (int j = 0; j < 8; j++) {
      bf16x8 wf = *(const bf16x8*)&tW[(wc * 128 + j * 16 + rA) * 32 + kc];
      acc[j] = __builtin_amdgcn_mfma_f32_16x16x32_bf16(af, wf, acc[j], 0, 0, 0);
    }
  }

  // ---- epilogue: out = acc + ub*D  (C/D: col=lane&15, row=(lane>>4)*4+q)
  const int cr = (lane >> 4) * 4;
  const int cc = lane & 15;
#pragma unroll
  for (int j = 0; j < 8; j++) {
    const int col = wc * 128 + j * 16 + cc;
    const float d = Dv[col];
#pragma unroll
    for (int q = 0; q < 4; q++) {
      const int row = row0 + wr * 16 + cr + q;
      const size_t idx = (size_t)row * H_DIM + col;
      out[idx] = fmaf(bf2f(ub[idx]), d, acc[j][q]);
    }
  }
}

extern "C" void kernel_launch(void* const* d_in, const int* in_sizes, int n_in,
                              void* d_out, int out_size, void* d_ws, size_t ws_size,
                              hipStream_t stream) {
  const float* u      = (const float*)d_in[0];  // (L, H)
  const float* A_diag = (const float*)d_in[1];
  const float* G_diag = (const float*)d_in[2];
  const float* dt     = (const float*)d_in[3];
  const float* B      = (const float*)d_in[4];  // (P, H, 2)
  const float* C      = (const float*)d_in[5];  // (H, P, 2)
  const float* D      = (const float*)d_in[6];  // (H,)
  float* out = (float*)d_out;

  // Workspace: Bu16 33.55MB | ub 8.39MB | W1b 0.5MB | W2b 0.5MB | prm | finals 4MB | carry 4MB (~51MB)
  char* w = (char*)d_ws;
  unsigned short* Bu16 = (unsigned short*)w;                               // L*1024 bf16
  unsigned short* ub   = (unsigned short*)(w + (size_t)L_SEQ * 1024 * 2);  // L*256 bf16
  unsigned short* W1b  = ub + (size_t)L_SEQ * H_DIM;                       // 1024*256
  unsigned short* W2b  = W1b + 1024 * H_DIM;                               // 256*1024
  float* prm    = (float*)(W2b + H_DIM * 1024);                            // 10*512 (pad 8192)
  float* finals = prm + 8192;                                              // NC*P*4
  float* carryb = finals + (size_t)NC * P_DIM * 4;                         // NC*P*4

  prep_all<<<2 + 1024 + 1024 + 4096, 256, 0, stream>>>(
      A_diag, G_diag, dt, B, C, u, prm, W1b, W2b, ub);

  // GEMM1 + fused local scan: Bu16 tile write + per-chunk finals
  gemm1_scan<<<dim3(L_SEQ / 128, 1024 / 128), 256, 0, stream>>>(
      ub, W1b, Bu16, prm, (float4*)finals);

  scan_carry<<<P_DIM, NC, 0, stream>>>(
      (const float4*)finals, prm, (float4*)carryb);

  // GEMM2 + fused scan_final: 512 blocks, one 32-row chunk each
  gemm2_fused<<<L_SEQ / 32, 256, 0, stream>>>(
      (const unsigned int*)Bu16, prm, (const float4*)carryb, W2b, ub, D, out);
}

// Round 12
// 74.689 us; speedup vs baseline: 2.9068x; 2.9068x over previous
//
#include <hip/hip_runtime.h>
#include <math.h>

// Problem constants: L=16384, H=256, P=512.
#define L_SEQ 16384
#define H_DIM 256
#define P_DIM 512
#define CL 32                 // scan chunk length == GEMM2 row-tile
#define NC (L_SEQ / CL)       // 512 chunks

typedef __attribute__((ext_vector_type(8))) short bf16x8;   // MFMA A/B fragment (4 VGPR)
typedef __attribute__((ext_vector_type(4))) float f32x4;    // MFMA C/D fragment

static __device__ __forceinline__ unsigned short f2bf(float f) {
  unsigned int u = __builtin_bit_cast(unsigned int, f);
  u += 0x7FFFu + ((u >> 16) & 1u);
  return (unsigned short)(u >> 16);
}
static __device__ __forceinline__ float bflo(unsigned int v) {
  return __builtin_bit_cast(float, v << 16);
}
static __device__ __forceinline__ float bfhi(unsigned int v) {
  return __builtin_bit_cast(float, v & 0xFFFF0000u);
}
static __device__ __forceinline__ float bf2f(unsigned short s) {
  return __builtin_bit_cast(float, (unsigned int)s << 16);
}

// Merged prep (branch by blockIdx, wave-uniform):
//  [0,2): params; [2,1026): W1b; [1026,2050): W2b; [2050,6146): cast u->ub
__global__ __launch_bounds__(256) void prep_all(
    const float* __restrict__ A_diag, const float* __restrict__ G_diag,
    const float* __restrict__ dt, const float* __restrict__ B,
    const float* __restrict__ C, const float* __restrict__ u,
    float* __restrict__ prm, unsigned short* __restrict__ W1b,
    unsigned short* __restrict__ W2b, unsigned short* __restrict__ ub) {
  const int b = blockIdx.x;
  const int t = threadIdx.x;
  if (b < 2) {
    int p = b * 256 + t;
    float dts = 1.0f / (1.0f + expf(-dt[p]));
    float G = fmaxf(G_diag[p], 0.0f);
    float g = dts * G;
    float root = sqrtf(1.0f - g);
    float denom = fmaxf(dts * dts, 1e-6f);
    float A_low  = (2.0f - g - 2.0f * root) / denom;
    float A_high = (2.0f - g + 2.0f * root) / denom;
    float Ad = A_diag[p];
    float A = A_low + fmaxf(Ad - A_low, 0.0f) - fmaxf(Ad - A_high, 0.0f);
    float m00 = 1.0f - g;
    float m01 = -dts * A;
    float m10 = dts * (1.0f - g);
    float m11 = 1.0f - dts * dts * A;
    float c00 = m00, c01 = m01, c10 = m10, c11 = m11;
#pragma unroll
    for (int i = 0; i < 5; i++) {   // M^32 by squaring (CL=32); rho(M)<=1
      float n00 = c00 * c00 + c01 * c10;
      float n01 = c00 * c01 + c01 * c11;
      float n10 = c10 * c00 + c11 * c10;
      float n11 = c10 * c01 + c11 * c11;
      c00 = n00; c01 = n01; c10 = n10; c11 = n11;
    }
    prm[0 * P_DIM + p] = m00;
    prm[1 * P_DIM + p] = m01;
    prm[2 * P_DIM + p] = m10;
    prm[3 * P_DIM + p] = m11;
    prm[4 * P_DIM + p] = dts;
    prm[5 * P_DIM + p] = dts * dts;
    prm[6 * P_DIM + p] = c00;
    prm[7 * P_DIM + p] = c01;
    prm[8 * P_DIM + p] = c10;
    prm[9 * P_DIM + p] = c11;
  } else if (b < 2 + 1024) {
    int idx = (b - 2) * 256 + t;          // W1b[n][k], n=2p+c, k=h
    int n = idx >> 8;
    int k = idx & 255;
    int p = n >> 1, c = n & 1;
    W1b[idx] = f2bf(B[(p * H_DIM + k) * 2 + c]);
  } else if (b < 2 + 2048) {
    int idx = (b - 1026) * 256 + t;       // W2b[n][k], n=h, k=2p+c
    int h = idx >> 10;
    int k = idx & 1023;
    int p = k >> 1, c = k & 1;
    float v = C[(h * P_DIM + p) * 2 + c];
    W2b[idx] = f2bf(c ? -v : v);
  } else {
    int idx = (b - 2050) * 256 + t;       // cast u
    float4 v = ((const float4*)u)[idx];
    ushort4 o;
    o.x = f2bf(v.x); o.y = f2bf(v.y); o.z = f2bf(v.z); o.w = f2bf(v.w);
    ((ushort4*)ub)[idx] = o;
  }
}

// GEMM1 + fused local scan. 128x128 tile, 256 threads = 4 waves (2x2), BK=32.
// Epilogue stages the C-tile in LDS (padded stride 132: writer row-groups land
// on disjoint bank octets; reader = 2 lanes/bank = free) so the local scan reads
// LDS — NO __threadfence, NO global re-read (round-11's 149us stall was the
// agent-scope fence forcing per-block L2 writebacks).
__global__ __launch_bounds__(256) void gemm1_scan(
    const unsigned short* __restrict__ A, const unsigned short* __restrict__ W,
    unsigned short* __restrict__ Out,           // Bu16, N=1024
    const float* __restrict__ prm, float4* __restrict__ finals) {
  constexpr int BM = 128, BN = 128, N = 1024, K = H_DIM;
  __shared__ unsigned short tA[BM * 32];     // 8KB, linear (gload_lds dest)
  __shared__ unsigned short tW[BN * 32];     // 8KB
  __shared__ unsigned short stg[128 * 132];  // 33KB C-tile stage, padded stride
  const int tid = threadIdx.x;
  const int lane = tid & 63;
  const int wid = tid >> 6;
  const int wr = wid >> 1;
  const int wc = wid & 1;
  const int bm = blockIdx.x * BM;
  const int bn = blockIdx.y * BN;

  f32x4 acc[4][4] = {};

  const int srow = lane >> 2;
  const int soff = (lane & 3) * 8;

  for (int k0 = 0; k0 < K; k0 += 32) {
    __syncthreads();
#pragma unroll
    for (int c = wid; c < BM / 16; c += 4) {
      const unsigned short* src = A + (size_t)(bm + c * 16 + srow) * K + k0 + soff;
      __builtin_amdgcn_global_load_lds(
          (const __attribute__((address_space(1))) void*)src,
          (__attribute__((address_space(3))) void*)(tA + c * 512), 16, 0, 0);
    }
#pragma unroll
    for (int c = wid; c < BN / 16; c += 4) {
      const unsigned short* src = W + (size_t)(bn + c * 16 + srow) * K + k0 + soff;
      __builtin_amdgcn_global_load_lds(
          (const __attribute__((address_space(1))) void*)src,
          (__attribute__((address_space(3))) void*)(tW + c * 512), 16, 0, 0);
    }
    __syncthreads();

    const int rA = lane & 15;
    const int kc = (lane >> 4) * 8;
    bf16x8 af[4], wf[4];
#pragma unroll
    for (int i = 0; i < 4; i++)
      af[i] = *(const bf16x8*)&tA[(wr * 64 + i * 16 + rA) * 32 + kc];
#pragma unroll
    for (int j = 0; j < 4; j++)
      wf[j] = *(const bf16x8*)&tW[(wc * 64 + j * 16 + rA) * 32 + kc];
#pragma unroll
    for (int i = 0; i < 4; i++)
#pragma unroll
      for (int j = 0; j < 4; j++)
        acc[i][j] = __builtin_amdgcn_mfma_f32_16x16x32_bf16(af[i], wf[j], acc[i][j], 0, 0, 0);
  }

  // C/D layout: col = lane&15, row = (lane>>4)*4 + q  [m89-verified]
  const int cr = (lane >> 4) * 4;
  const int cc = lane & 15;
#pragma unroll
  for (int i = 0; i < 4; i++)
#pragma unroll
    for (int j = 0; j < 4; j++) {
      const int rl = wr * 64 + i * 16 + cr;          // local row
      const int clc = wc * 64 + j * 16 + cc;         // local col
#pragma unroll
      for (int q = 0; q < 4; q++) {
        const unsigned short hv = f2bf(acc[i][j][q]);
        Out[(size_t)(bm + rl + q) * N + bn + clc] = hv;
        stg[(rl + q) * 132 + clc] = hv;              // LDS stage for fused scan
      }
    }

  // ---- fused local scan over this block's 4 chunks x 64 p-states (from LDS)
  __syncthreads();
  {
    const int i = tid >> 6;            // chunk within tile (0..3) — one per wave
    const int pl = tid & 63;           // p within tile
    const int p = (bn >> 1) + pl;      // global p
    const int cglob = blockIdx.x * 4 + i;
    float m00 = prm[0 * P_DIM + p], m01 = prm[1 * P_DIM + p];
    float m10 = prm[2 * P_DIM + p], m11 = prm[3 * P_DIM + p];
    float dts = prm[4 * P_DIM + p], dts2 = prm[5 * P_DIM + p];
    float x1r = 0.f, x2r = 0.f, x1i = 0.f, x2i = 0.f;
    const unsigned int* stg32 = (const unsigned int*)stg;   // dword idx = row*66 + pl
#pragma unroll 8
    for (int s = 0; s < CL; s++) {
      unsigned int v = stg32[(i * 32 + s) * 66 + pl];
      float bx = bflo(v), by = bfhi(v);
      float n1r = fmaf(m00, x1r, fmaf(m01, x2r, dts * bx));
      float n2r = fmaf(m10, x1r, fmaf(m11, x2r, dts2 * bx));
      float n1i = fmaf(m00, x1i, fmaf(m01, x2i, dts * by));
      float n2i = fmaf(m10, x1i, fmaf(m11, x2i, dts2 * by));
      x1r = n1r; x2r = n2r; x1i = n1i; x2i = n2i;
    }
    finals[(size_t)cglob * P_DIM + p] = make_float4(x1r, x2r, x1i, x2i);
  }
}

// Phase B: Hillis-Steele over NC=512 chunks, one block per p, 512 threads.
__global__ __launch_bounds__(NC) void scan_carry(
    const float4* __restrict__ finals, const float* __restrict__ prm,
    float4* __restrict__ carry) {
  int p = blockIdx.x;
  int c = threadIdx.x;
  __shared__ float4 sb[NC];
  float m00 = prm[6 * P_DIM + p], m01 = prm[7 * P_DIM + p];
  float m10 = prm[8 * P_DIM + p], m11 = prm[9 * P_DIM + p];
  float4 b = finals[c * P_DIM + p];
  for (int o = 1; o < NC; o <<= 1) {
    sb[c] = b;
    __syncthreads();
    float4 nb = (c >= o) ? sb[c - o] : make_float4(0.f, 0.f, 0.f, 0.f);
    __syncthreads();
    b.x = fmaf(m00, nb.x, fmaf(m01, nb.y, b.x));
    b.y = fmaf(m10, nb.x, fmaf(m11, nb.y, b.y));
    b.z = fmaf(m00, nb.z, fmaf(m01, nb.w, b.z));
    b.w = fmaf(m10, nb.z, fmaf(m11, nb.w, b.w));
    float n00 = m00 * m00 + m01 * m10;
    float n01 = m00 * m01 + m01 * m11;
    float n10 = m10 * m00 + m11 * m10;
    float n11 = m10 * m01 + m11 * m11;
    m00 = n00; m01 = n01; m10 = n10; m11 = n11;
  }
  if (c + 1 < NC) carry[(c + 1) * P_DIM + p] = b;
  if (c == 0) carry[p] = make_float4(0.f, 0.f, 0.f, 0.f);
}

// GEMM2 with fused scan_final: block = 32 rows (one CL chunk) x full N=256.
// Prologue: recompute ys for the 32 rows from Bu16 + carry (fp32 recurrence),
// deposit bf16 into XOR-swizzled LDS A-tile (T2: byte ^= (row&7)<<4).
// K-loop: A from LDS (no staging), W2b tile via global_load_lds (16KB/step).
// Epilogue: out = acc + ub*D (fp32 out).
__global__ __launch_bounds__(256) void gemm2_fused(
    const unsigned int* __restrict__ Bu16, const float* __restrict__ prm,
    const float4* __restrict__ carry, const unsigned short* __restrict__ W2b,
    const unsigned short* __restrict__ ub, const float* __restrict__ Dv,
    float* __restrict__ out) {
  __shared__ unsigned int yA[32 * 512];       // 64KB: ys[row][p] packed bf16 (re,im), swizzled
  __shared__ unsigned short tW[256 * 32];     // 16KB W2b K-tile (linear, gload_lds dest)
  const int tid = threadIdx.x;
  const int lane = tid & 63;
  const int wid = tid >> 6;
  const int row0 = blockIdx.x * 32;

  // ---- prologue: 2 p-columns per thread, 32-step recurrence
#pragma unroll
  for (int h = 0; h < 2; h++) {
    const int p = tid + h * 256;
    float m00 = prm[0 * P_DIM + p], m01 = prm[1 * P_DIM + p];
    float m10 = prm[2 * P_DIM + p], m11 = prm[3 * P_DIM + p];
    float dts = prm[4 * P_DIM + p], dts2 = prm[5 * P_DIM + p];
    float4 s = carry[(size_t)blockIdx.x * P_DIM + p];
    float x1r = s.x, x2r = s.y, x1i = s.z, x2i = s.w;
    const unsigned int* src = Bu16 + (size_t)row0 * P_DIM + p;
#pragma unroll 8
    for (int i = 0; i < 32; i++) {
      unsigned int v = src[(size_t)i * P_DIM];
      float bx = bflo(v), by = bfhi(v);
      float n1r = fmaf(m00, x1r, fmaf(m01, x2r, dts * bx));
      float n2r = fmaf(m10, x1r, fmaf(m11, x2r, dts2 * bx));
      float n1i = fmaf(m00, x1i, fmaf(m01, x2i, dts * by));
      float n2i = fmaf(m10, x1i, fmaf(m11, x2i, dts2 * by));
      // swizzled store: uint index (i*512+p) ^ ((i&7)<<2)  == byte ^ ((i&7)<<4)
      yA[(i * 512 + p) ^ ((i & 7) << 2)] =
          (unsigned int)f2bf(n2r) | ((unsigned int)f2bf(n2i) << 16);
      x1r = n1r; x2r = n2r; x1i = n1i; x2i = n2i;
    }
  }

  // ---- K-loop: 32 steps of BK=32 over K=1024
  const int srow = lane >> 2;
  const int soff = (lane & 3) * 8;
  const int wr = wid >> 1;          // row half (16 rows)
  const int wc = wid & 1;           // col half (128 cols)
  const int rA = lane & 15;
  const int kc = (lane >> 4) * 8;
  const int arow = wr * 16 + rA;
  const unsigned short* yAs = (const unsigned short*)yA;
  f32x4 acc[8] = {};

  for (int k0 = 0; k0 < 1024; k0 += 32) {
    __syncthreads();   // first iteration also fences prologue LDS writes
#pragma unroll
    for (int c = wid; c < 16; c += 4) {
      const unsigned short* src = W2b + (size_t)(c * 16 + srow) * 1024 + k0 + soff;
      __builtin_amdgcn_global_load_lds(
          (const __attribute__((address_space(1))) void*)src,
          (__attribute__((address_space(3))) void*)(tW + c * 512), 16, 0, 0);
    }
    __syncthreads();

    // A-frag from swizzled LDS: short index (arow*1024 + k) ^ ((arow&7)<<3)
    bf16x8 af = *(const bf16x8*)&yAs[((size_t)arow * 1024 + k0 + kc) ^ ((arow & 7) << 3)];
#pragma unroll
    for (int j = 0; j < 8; j++) {
      bf16x8 wf = *(const bf16x8*)&tW[(wc * 128 + j * 16 + rA) * 32 + kc];
      acc[j] = __builtin_amdgcn_mfma_f32_16x16x32_bf16(af, wf, acc[j], 0, 0, 0);
    }
  }

  // ---- epilogue: out = acc + ub*D  (C/D: col=lane&15, row=(lane>>4)*4+q)
  const int cr = (lane >> 4) * 4;
  const int cc = lane & 15;
#pragma unroll
  for (int j = 0; j < 8; j++) {
    const int col = wc * 128 + j * 16 + cc;
    const float d = Dv[col];
#pragma unroll
    for (int q = 0; q < 4; q++) {
      const int row = row0 + wr * 16 + cr + q;
      const size_t idx = (size_t)row * H_DIM + col;
      out[idx] = fmaf(bf2f(ub[idx]), d, acc[j][q]);
    }
  }
}

extern "C" void kernel_launch(void* const* d_in, const int* in_sizes, int n_in,
                              void* d_out, int out_size, void* d_ws, size_t ws_size,
                              hipStream_t stream) {
  const float* u      = (const float*)d_in[0];  // (L, H)
  const float* A_diag = (const float*)d_in[1];
  const float* G_diag = (const float*)d_in[2];
  const float* dt     = (const float*)d_in[3];
  const float* B      = (const float*)d_in[4];  // (P, H, 2)
  const float* C      = (const float*)d_in[5];  // (H, P, 2)
  const float* D      = (const float*)d_in[6];  // (H,)
  float* out = (float*)d_out;

  // Workspace: Bu16 33.55MB | ub 8.39MB | W1b 0.5MB | W2b 0.5MB | prm | finals 4MB | carry 4MB (~51MB)
  char* w = (char*)d_ws;
  unsigned short* Bu16 = (unsigned short*)w;                               // L*1024 bf16
  unsigned short* ub   = (unsigned short*)(w + (size_t)L_SEQ * 1024 * 2);  // L*256 bf16
  unsigned short* W1b  = ub + (size_t)L_SEQ * H_DIM;                       // 1024*256
  unsigned short* W2b  = W1b + 1024 * H_DIM;                               // 256*1024
  float* prm    = (float*)(W2b + H_DIM * 1024);                            // 10*512 (pad 8192)
  float* finals = prm + 8192;                                              // NC*P*4
  float* carryb = finals + (size_t)NC * P_DIM * 4;                         // NC*P*4

  prep_all<<<2 + 1024 + 1024 + 4096, 256, 0, stream>>>(
      A_diag, G_diag, dt, B, C, u, prm, W1b, W2b, ub);

  // GEMM1 + fused local scan (LDS-staged, no fence)
  gemm1_scan<<<dim3(L_SEQ / 128, 1024 / 128), 256, 0, stream>>>(
      ub, W1b, Bu16, prm, (float4*)finals);

  scan_carry<<<P_DIM, NC, 0, stream>>>(
      (const float4*)finals, prm, (float4*)carryb);

  // GEMM2 + fused scan_final: 512 blocks, one 32-row chunk each
  gemm2_fused<<<L_SEQ / 32, 256, 0, stream>>>(
      (const unsigned int*)Bu16, prm, (const float4*)carryb, W2b, ub, D, out);
}

// Round 13
// 72.669 us; speedup vs baseline: 2.9875x; 1.0278x over previous
//
#include <hip/hip_runtime.h>
#include <math.h>

// Problem constants: L=16384, H=256, P=512.
#define L_SEQ 16384
#define H_DIM 256
#define P_DIM 512
#define CL 32                 // scan chunk length == GEMM2 row-tile
#define NC (L_SEQ / CL)       // 512 chunks

typedef __attribute__((ext_vector_type(8))) short bf16x8;   // MFMA A/B fragment (4 VGPR)
typedef __attribute__((ext_vector_type(4))) float f32x4;    // MFMA C/D fragment

static __device__ __forceinline__ unsigned short f2bf(float f) {
  unsigned int u = __builtin_bit_cast(unsigned int, f);
  u += 0x7FFFu + ((u >> 16) & 1u);
  return (unsigned short)(u >> 16);
}
static __device__ __forceinline__ float bflo(unsigned int v) {
  return __builtin_bit_cast(float, v << 16);
}
static __device__ __forceinline__ float bfhi(unsigned int v) {
  return __builtin_bit_cast(float, v & 0xFFFF0000u);
}
static __device__ __forceinline__ float bf2f(unsigned short s) {
  return __builtin_bit_cast(float, (unsigned int)s << 16);
}

// Weights stored K-PACKED: unit = (k>>3)*N + n, element = unit*8 + (k&7).
// Staged tiles are then contiguous-ish, gload_lds dest stays linear, and MFMA
// fragment reads hit 2 lanes/bank (free) instead of 8-way conflicts.
//
// Merged prep (branch by blockIdx, wave-uniform):
//  [0,2): params; [2,1026): W1b_r; [1026,2050): W2b_r; [2050,6146): cast u->ub
__global__ __launch_bounds__(256) void prep_all(
    const float* __restrict__ A_diag, const float* __restrict__ G_diag,
    const float* __restrict__ dt, const float* __restrict__ B,
    const float* __restrict__ C, const float* __restrict__ u,
    float* __restrict__ prm, unsigned short* __restrict__ W1b,
    unsigned short* __restrict__ W2b, unsigned short* __restrict__ ub) {
  const int b = blockIdx.x;
  const int t = threadIdx.x;
  if (b < 2) {
    int p = b * 256 + t;
    float dts = 1.0f / (1.0f + expf(-dt[p]));
    float G = fmaxf(G_diag[p], 0.0f);
    float g = dts * G;
    float root = sqrtf(1.0f - g);
    float denom = fmaxf(dts * dts, 1e-6f);
    float A_low  = (2.0f - g - 2.0f * root) / denom;
    float A_high = (2.0f - g + 2.0f * root) / denom;
    float Ad = A_diag[p];
    float A = A_low + fmaxf(Ad - A_low, 0.0f) - fmaxf(Ad - A_high, 0.0f);
    float m00 = 1.0f - g;
    float m01 = -dts * A;
    float m10 = dts * (1.0f - g);
    float m11 = 1.0f - dts * dts * A;
    float c00 = m00, c01 = m01, c10 = m10, c11 = m11;
#pragma unroll
    for (int i = 0; i < 5; i++) {   // M^32 by squaring (CL=32); rho(M)<=1
      float n00 = c00 * c00 + c01 * c10;
      float n01 = c00 * c01 + c01 * c11;
      float n10 = c10 * c00 + c11 * c10;
      float n11 = c10 * c01 + c11 * c11;
      c00 = n00; c01 = n01; c10 = n10; c11 = n11;
    }
    prm[0 * P_DIM + p] = m00;
    prm[1 * P_DIM + p] = m01;
    prm[2 * P_DIM + p] = m10;
    prm[3 * P_DIM + p] = m11;
    prm[4 * P_DIM + p] = dts;
    prm[5 * P_DIM + p] = dts * dts;
    prm[6 * P_DIM + p] = c00;
    prm[7 * P_DIM + p] = c01;
    prm[8 * P_DIM + p] = c10;
    prm[9 * P_DIM + p] = c11;
  } else if (b < 2 + 1024) {
    int idx = (b - 2) * 256 + t;          // n=2p+c in [0,1024), k=h in [0,256)
    int n = idx >> 8;
    int k = idx & 255;
    int p = n >> 1, c = n & 1;
    W1b[((size_t)(k >> 3) * 1024 + n) * 8 + (k & 7)] = f2bf(B[(p * H_DIM + k) * 2 + c]);
  } else if (b < 2 + 2048) {
    int idx = (b - 1026) * 256 + t;       // n=h in [0,256), k=2p+c in [0,1024)
    int h = idx >> 10;
    int k = idx & 1023;
    int p = k >> 1, c = k & 1;
    float v = C[(h * P_DIM + p) * 2 + c];
    W2b[((size_t)(k >> 3) * 256 + h) * 8 + (k & 7)] = f2bf(c ? -v : v);
  } else {
    int idx = (b - 2050) * 256 + t;       // cast u
    float4 v = ((const float4*)u)[idx];
    ushort4 o;
    o.x = f2bf(v.x); o.y = f2bf(v.y); o.z = f2bf(v.z); o.w = f2bf(v.w);
    ((ushort4*)ub)[idx] = o;
  }
}

// GEMM1 + fused local scan. 128x128 tile, 256 threads = 4 waves (2x2), BK=32.
// LDS tiles k-packed [kg][row][8] -> conflict-free fragment reads.
// Epilogue stages the C-tile in LDS (padded stride 132) for the fused local scan
// (no fence, no global re-read).
__global__ __launch_bounds__(256) void gemm1_scan(
    const unsigned short* __restrict__ A, const unsigned short* __restrict__ W,
    unsigned short* __restrict__ Out,           // Bu16, N=1024
    const float* __restrict__ prm, float4* __restrict__ finals) {
  constexpr int N = 1024, K = H_DIM;
  __shared__ unsigned short tA[128 * 32];    // 8KB k-packed [kg][r][8]
  __shared__ unsigned short tW[128 * 32];    // 8KB k-packed [kg][n][8]
  __shared__ unsigned short stg[128 * 132];  // 33KB C-tile stage, padded stride
  const int tid = threadIdx.x;
  const int lane = tid & 63;
  const int wid = tid >> 6;
  const int wr = wid >> 1;
  const int wc = wid & 1;
  const int bm = blockIdx.x * 128;
  const int bn = blockIdx.y * 128;

  f32x4 acc[4][4] = {};
  const int rA = lane & 15;
  const int g = lane >> 4;

  for (int k0 = 0; k0 < K; k0 += 32) {
    __syncthreads();
#pragma unroll
    for (int c = wid; c < 8; c += 4) {        // A-tile: 512 units (kg*128 + r)
      const int unit = c * 64 + lane;
      const int kg = unit >> 7, r = unit & 127;
      const unsigned short* src = A + ((size_t)(bm + r) * 32 + (k0 >> 3) + kg) * 8;
      __builtin_amdgcn_global_load_lds(
          (const __attribute__((address_space(1))) void*)src,
          (__attribute__((address_space(3))) void*)(tA + c * 512), 16, 0, 0);
    }
#pragma unroll
    for (int c = wid; c < 8; c += 4) {        // W-tile: 512 units (kg*128 + n)
      const int unit = c * 64 + lane;
      const int kg = unit >> 7, n = unit & 127;
      const unsigned short* src = W + ((size_t)((k0 >> 3) + kg) * 1024 + bn + n) * 8;
      __builtin_amdgcn_global_load_lds(
          (const __attribute__((address_space(1))) void*)src,
          (__attribute__((address_space(3))) void*)(tW + c * 512), 16, 0, 0);
    }
    __syncthreads();

    bf16x8 af[4], wf[4];
#pragma unroll
    for (int i = 0; i < 4; i++)
      af[i] = *(const bf16x8*)&tA[(g * 128 + wr * 64 + i * 16 + rA) * 8];
#pragma unroll
    for (int j = 0; j < 4; j++)
      wf[j] = *(const bf16x8*)&tW[(g * 128 + wc * 64 + j * 16 + rA) * 8];
#pragma unroll
    for (int i = 0; i < 4; i++)
#pragma unroll
      for (int j = 0; j < 4; j++)
        acc[i][j] = __builtin_amdgcn_mfma_f32_16x16x32_bf16(af[i], wf[j], acc[i][j], 0, 0, 0);
  }

  // C/D layout: col = lane&15, row = (lane>>4)*4 + q  [m89-verified]
  const int cr = (lane >> 4) * 4;
  const int cc = lane & 15;
#pragma unroll
  for (int i = 0; i < 4; i++)
#pragma unroll
    for (int j = 0; j < 4; j++) {
      const int rl = wr * 64 + i * 16 + cr;          // local row
      const int clc = wc * 64 + j * 16 + cc;         // local col
#pragma unroll
      for (int q = 0; q < 4; q++) {
        const unsigned short hv = f2bf(acc[i][j][q]);
        Out[(size_t)(bm + rl + q) * N + bn + clc] = hv;
        stg[(rl + q) * 132 + clc] = hv;              // LDS stage for fused scan
      }
    }

  // ---- fused local scan over this block's 4 chunks x 64 p-states (from LDS)
  __syncthreads();
  {
    const int i = tid >> 6;            // chunk within tile (0..3) — one per wave
    const int pl = tid & 63;           // p within tile
    const int p = (bn >> 1) + pl;      // global p
    const int cglob = blockIdx.x * 4 + i;
    float m00 = prm[0 * P_DIM + p], m01 = prm[1 * P_DIM + p];
    float m10 = prm[2 * P_DIM + p], m11 = prm[3 * P_DIM + p];
    float dts = prm[4 * P_DIM + p], dts2 = prm[5 * P_DIM + p];
    float x1r = 0.f, x2r = 0.f, x1i = 0.f, x2i = 0.f;
    const unsigned int* stg32 = (const unsigned int*)stg;   // dword idx = row*66 + pl
#pragma unroll 8
    for (int s = 0; s < CL; s++) {
      unsigned int v = stg32[(i * 32 + s) * 66 + pl];
      float bx = bflo(v), by = bfhi(v);
      float n1r = fmaf(m00, x1r, fmaf(m01, x2r, dts * bx));
      float n2r = fmaf(m10, x1r, fmaf(m11, x2r, dts2 * bx));
      float n1i = fmaf(m00, x1i, fmaf(m01, x2i, dts * by));
      float n2i = fmaf(m10, x1i, fmaf(m11, x2i, dts2 * by));
      x1r = n1r; x2r = n2r; x1i = n1i; x2i = n2i;
    }
    finals[(size_t)cglob * P_DIM + p] = make_float4(x1r, x2r, x1i, x2i);
  }
}

// Phase B: Hillis-Steele over NC=512 chunks, one block per p, 512 threads.
__global__ __launch_bounds__(NC) void scan_carry(
    const float4* __restrict__ finals, const float* __restrict__ prm,
    float4* __restrict__ carry) {
  int p = blockIdx.x;
  int c = threadIdx.x;
  __shared__ float4 sb[NC];
  float m00 = prm[6 * P_DIM + p], m01 = prm[7 * P_DIM + p];
  float m10 = prm[8 * P_DIM + p], m11 = prm[9 * P_DIM + p];
  float4 b = finals[c * P_DIM + p];
  for (int o = 1; o < NC; o <<= 1) {
    sb[c] = b;
    __syncthreads();
    float4 nb = (c >= o) ? sb[c - o] : make_float4(0.f, 0.f, 0.f, 0.f);
    __syncthreads();
    b.x = fmaf(m00, nb.x, fmaf(m01, nb.y, b.x));
    b.y = fmaf(m10, nb.x, fmaf(m11, nb.y, b.y));
    b.z = fmaf(m00, nb.z, fmaf(m01, nb.w, b.z));
    b.w = fmaf(m10, nb.z, fmaf(m11, nb.w, b.w));
    float n00 = m00 * m00 + m01 * m10;
    float n01 = m00 * m01 + m01 * m11;
    float n10 = m10 * m00 + m11 * m10;
    float n11 = m10 * m01 + m11 * m11;
    m00 = n00; m01 = n01; m10 = n10; m11 = n11;
  }
  if (c + 1 < NC) carry[(c + 1) * P_DIM + p] = b;
  if (c == 0) carry[p] = make_float4(0.f, 0.f, 0.f, 0.f);
}

// GEMM2 + fused scan_final, 2-phase pipelined.
// Dynamic smem 64KB: prologue uses it as yA (32x512 swizzled ys tile);
// after af-extraction to REGISTERS (32 x bf16x8, statically indexed),
// the SAME region becomes double-buffered tW (2 x 16KB, k-packed).
// K-loop: issue stage(t+1) -> 8 wf reads + 8 MFMA from cur -> one barrier
// (compiler's vmcnt(0) drain overlaps compute instead of preceding it).
__global__ __launch_bounds__(256) void gemm2_fused(
    const unsigned int* __restrict__ Bu16, const float* __restrict__ prm,
    const float4* __restrict__ carry, const unsigned short* __restrict__ W2b,
    const unsigned short* __restrict__ ub, const float* __restrict__ Dv,
    float* __restrict__ out) {
  extern __shared__ char smem[];                       // 64KB
  unsigned int* yA = (unsigned int*)smem;              // prologue alias
  unsigned short* tW0 = (unsigned short*)smem;         // 16KB
  unsigned short* tW1 = (unsigned short*)(smem + 16384);
  const int tid = threadIdx.x;
  const int lane = tid & 63;
  const int wid = tid >> 6;
  const int row0 = blockIdx.x * 32;

  // ---- prologue: 2 p-columns per thread, 32-step recurrence -> yA (swizzled)
#pragma unroll
  for (int h = 0; h < 2; h++) {
    const int p = tid + h * 256;
    float m00 = prm[0 * P_DIM + p], m01 = prm[1 * P_DIM + p];
    float m10 = prm[2 * P_DIM + p], m11 = prm[3 * P_DIM + p];
    float dts = prm[4 * P_DIM + p], dts2 = prm[5 * P_DIM + p];
    float4 s = carry[(size_t)blockIdx.x * P_DIM + p];
    float x1r = s.x, x2r = s.y, x1i = s.z, x2i = s.w;
    const unsigned int* src = Bu16 + (size_t)row0 * P_DIM + p;
#pragma unroll 8
    for (int i = 0; i < 32; i++) {
      unsigned int v = src[(size_t)i * P_DIM];
      float bx = bflo(v), by = bfhi(v);
      float n1r = fmaf(m00, x1r, fmaf(m01, x2r, dts * bx));
      float n2r = fmaf(m10, x1r, fmaf(m11, x2r, dts2 * bx));
      float n1i = fmaf(m00, x1i, fmaf(m01, x2i, dts * by));
      float n2i = fmaf(m10, x1i, fmaf(m11, x2i, dts2 * by));
      // swizzled store: uint index (i*512+p) ^ ((i&7)<<2)  == byte ^ ((i&7)<<4)
      yA[(i * 512 + p) ^ ((i & 7) << 2)] =
          (unsigned int)f2bf(n2r) | ((unsigned int)f2bf(n2i) << 16);
      x1r = n1r; x2r = n2r; x1i = n1i; x2i = n2i;
    }
  }
  __syncthreads();

  // ---- extract all 32 A-fragments to registers (yA dead afterwards)
  const int wr = wid >> 1;          // row half (16 rows)
  const int wc = wid & 1;           // col half (128 cols)
  const int rA = lane & 15;
  const int g = lane >> 4;
  const int kc = g * 8;
  const int arow = wr * 16 + rA;
  const unsigned short* yAs = (const unsigned short*)yA;
  bf16x8 af[32];
#pragma unroll
  for (int t = 0; t < 32; t++)
    af[t] = *(const bf16x8*)&yAs[((unsigned)(arow * 1024 + t * 32 + kc)) ^ ((arow & 7) << 3)];
  __syncthreads();   // all yA reads done before tW aliases it

  // ---- 2-phase pipelined K-loop over K=1024 (32 steps of 32)
  auto STAGE = [&](unsigned short* buf, int k0) {
#pragma unroll
    for (int c = wid; c < 16; c += 4) {
      // k-packed W2b: tile (k0..k0+32) x 256n is contiguous 16KB at unit (k0/8)*256
      const unsigned short* src = W2b + ((size_t)(k0 >> 3) * 256 + c * 64 + lane) * 8;
      __builtin_amdgcn_global_load_lds(
          (const __attribute__((address_space(1))) void*)src,
          (__attribute__((address_space(3))) void*)(buf + c * 512), 16, 0, 0);
    }
  };

  f32x4 acc[8] = {};
  STAGE(tW0, 0);
  __syncthreads();
#pragma unroll
  for (int t = 0; t < 32; t++) {
    const unsigned short* cur = (t & 1) ? tW1 : tW0;
    unsigned short* nxt = (t & 1) ? tW0 : tW1;
    if (t < 31) STAGE(nxt, (t + 1) * 32);
#pragma unroll
    for (int j = 0; j < 8; j++) {
      bf16x8 wf = *(const bf16x8*)&cur[(g * 256 + wc * 128 + j * 16 + rA) * 8];
      acc[j] = __builtin_amdgcn_mfma_f32_16x16x32_bf16(af[t], wf, acc[j], 0, 0, 0);
    }
    __syncthreads();   // drains stage(t+1); cur reads done before its overwrite
  }

  // ---- epilogue: out = acc + ub*D  (C/D: col=lane&15, row=(lane>>4)*4+q)
  const int cr = (lane >> 4) * 4;
  const int cc = lane & 15;
#pragma unroll
  for (int j = 0; j < 8; j++) {
    const int col = wc * 128 + j * 16 + cc;
    const float d = Dv[col];
#pragma unroll
    for (int q = 0; q < 4; q++) {
      const int row = row0 + wr * 16 + cr + q;
      const size_t idx = (size_t)row * H_DIM + col;
      out[idx] = fmaf(bf2f(ub[idx]), d, acc[j][q]);
    }
  }
}

extern "C" void kernel_launch(void* const* d_in, const int* in_sizes, int n_in,
                              void* d_out, int out_size, void* d_ws, size_t ws_size,
                              hipStream_t stream) {
  const float* u      = (const float*)d_in[0];  // (L, H)
  const float* A_diag = (const float*)d_in[1];
  const float* G_diag = (const float*)d_in[2];
  const float* dt     = (const float*)d_in[3];
  const float* B      = (const float*)d_in[4];  // (P, H, 2)
  const float* C      = (const float*)d_in[5];  // (H, P, 2)
  const float* D      = (const float*)d_in[6];  // (H,)
  float* out = (float*)d_out;

  // Workspace: Bu16 33.55MB | ub 8.39MB | W1b 0.5MB | W2b 0.5MB | prm | finals 4MB | carry 4MB (~51MB)
  char* w = (char*)d_ws;
  unsigned short* Bu16 = (unsigned short*)w;                               // L*1024 bf16
  unsigned short* ub   = (unsigned short*)(w + (size_t)L_SEQ * 1024 * 2);  // L*256 bf16
  unsigned short* W1b  = ub + (size_t)L_SEQ * H_DIM;                       // 1024*256 (k-packed)
  unsigned short* W2b  = W1b + 1024 * H_DIM;                               // 256*1024 (k-packed)
  float* prm    = (float*)(W2b + H_DIM * 1024);                            // 10*512 (pad 8192)
  float* finals = prm + 8192;                                              // NC*P*4
  float* carryb = finals + (size_t)NC * P_DIM * 4;                         // NC*P*4

  prep_all<<<2 + 1024 + 1024 + 4096, 256, 0, stream>>>(
      A_diag, G_diag, dt, B, C, u, prm, W1b, W2b, ub);

  // GEMM1 + fused local scan (k-packed LDS tiles)
  gemm1_scan<<<dim3(L_SEQ / 128, 1024 / 128), 256, 0, stream>>>(
      ub, W1b, Bu16, prm, (float4*)finals);

  scan_carry<<<P_DIM, NC, 0, stream>>>(
      (const float4*)finals, prm, (float4*)carryb);

  // GEMM2 + fused scan_final: 512 blocks, 64KB dynamic smem (yA -> tW dbuf)
  gemm2_fused<<<L_SEQ / 32, 256, 65536, stream>>>(
      (const unsigned int*)Bu16, prm, (const float4*)carryb, W2b, ub, D, out);
}